// Round 1
// baseline (127.149 us; speedup 1.0000x reference)
//
#include <hip/hip_runtime.h>
#include <hip/hip_bf16.h>
#include <math.h>

// Problem constants (reference: R,C,D,ORDER = 2048,2048,64,3; O=4)
#define R_DIM 2048
#define C_DIM 2048
#define D_DIM 64
#define O_DIM 4

// Workspace layout (float offsets). Total ~303 KB.
#define G16_OFF 0                    // R*16 floats: per-row Gram matrix (full 4x4)
#define P16_OFF (131072 / 4)         // C*16 floats: coef outer products
#define WC4_OFF (262144 / 4)         // C*4 floats: -2*coef_o per column
#define NZC_OFF (294912 / 4)         // C floats:   ||z_col||^2

// ---------------- per-row precompute: Gram matrix G[o,o'] = Z_o[r]·Z_o'[r] ----
__global__ void prep_rows_kernel(const float* __restrict__ z_rows,
                                 float* __restrict__ ws,
                                 float* __restrict__ out) {
  const int r = blockIdx.x;
  const int lane = threadIdx.x;  // 64 threads = 1 wave per row
  float zv[O_DIM];
#pragma unroll
  for (int o = 0; o < O_DIM; ++o)
    zv[o] = z_rows[(size_t)(o * R_DIM + r) * D_DIM + lane];
  float* G16 = ws + G16_OFF;
#pragma unroll
  for (int o = 0; o < O_DIM; ++o) {
#pragma unroll
    for (int op = o; op < O_DIM; ++op) {
      float p = zv[o] * zv[op];
      for (int off = 32; off > 0; off >>= 1) p += __shfl_down(p, off);
      if (lane == 0) {
        G16[r * 16 + o * 4 + op] = p;
        if (op != o) G16[r * 16 + op * 4 + o] = p;
      }
    }
  }
  // zero the scalar output once per launch (stream order guarantees this
  // completes before pair_kernel's atomics run)
  if (r == 0 && lane == 0) out[0] = 0.0f;
}

// ---------------- per-col precompute: coef products, -2*coef, ||zc||^2 -------
__global__ void prep_cols_kernel(const float* __restrict__ col_times,
                                 const float* __restrict__ z_cols,
                                 float* __restrict__ ws) {
  const int c = blockIdx.x;
  const int lane = threadIdx.x;  // 64 threads = 1 wave per column
  const float t = col_times[c];
  float coef[4];
  coef[0] = 1.0f;
  coef[1] = t;
  coef[2] = t * t * 0.5f;
  coef[3] = t * t * t * (1.0f / 6.0f);
  const float zc = z_cols[(size_t)c * D_DIM + lane];
  float p = zc * zc;
  for (int off = 32; off > 0; off >>= 1) p += __shfl_down(p, off);
  if (lane == 0) ws[NZC_OFF + c] = p;
  if (lane < 16) ws[P16_OFF + c * 16 + lane] = coef[lane >> 2] * coef[lane & 3];
  if (lane < 4) ws[WC4_OFF + c * 4 + lane] = -2.0f * coef[lane];
}

// ---------------- main fused GEMM(K=256) + epilogue + reduction --------------
#define BM 64
#define BN 64
#define BK 16
#define LDT (BM + 4)  // +4 pad: keeps 16B alignment for b128 LDS reads, breaks conflicts

__launch_bounds__(256, 2)
__global__ void pair_kernel(const int* __restrict__ events,
                            const float* __restrict__ z_rows,
                            const float* __restrict__ z_cols,
                            const float* __restrict__ gamma_rows,
                            const float* __restrict__ gamma_cols,
                            const float* __restrict__ ws,
                            float* __restrict__ out) {
  __shared__ float As[BK][LDT];  // As[dk][m]
  __shared__ float Bs[BK][LDT];  // Bs[dk][n]
  __shared__ float red[4];

  const int m0 = blockIdx.y * BM;
  const int c0 = blockIdx.x * BN;
  const int t = threadIdx.x;
  const int tn = t & 15;   // 16 col-groups
  const int tm = t >> 4;   // 16 row-groups

  const float* G16 = ws + G16_OFF;
  const float* P16 = ws + P16_OFF;
  const float* Wc4 = ws + WC4_OFF;
  const float* nzc = ws + NZC_OFF;

  float acc[4][4];
#pragma unroll
  for (int i = 0; i < 4; ++i)
#pragma unroll
    for (int j = 0; j < 4; ++j) acc[i][j] = 0.0f;

  // K loop over o*64+d, BK=16 so each k-tile sits inside a single order o
  for (int kt = 0; kt < O_DIM * D_DIM; kt += BK) {
    const int o = kt >> 6;
    const int d0 = kt & 63;
#pragma unroll
    for (int i = 0; i < 4; ++i) {
      const int lin = t + 256 * i;
      const int m = lin >> 4;
      const int dk = lin & 15;
      As[dk][m] = z_rows[(size_t)(o * R_DIM + m0 + m) * D_DIM + d0 + dk];
    }
#pragma unroll
    for (int i = 0; i < 4; ++i) {
      const int lin = t + 256 * i;
      const int n = lin >> 4;
      const int dk = lin & 15;
      Bs[dk][n] = Wc4[(c0 + n) * 4 + o] * z_cols[(size_t)(c0 + n) * D_DIM + d0 + dk];
    }
    __syncthreads();
#pragma unroll
    for (int dk = 0; dk < BK; ++dk) {
      float a[4], b[4];
#pragma unroll
      for (int ii = 0; ii < 4; ++ii) a[ii] = As[dk][tm * 4 + ii];
#pragma unroll
      for (int jj = 0; jj < 4; ++jj) b[jj] = Bs[dk][tn * 4 + jj];
#pragma unroll
      for (int ii = 0; ii < 4; ++ii)
#pragma unroll
        for (int jj = 0; jj < 4; ++jj)
          acc[ii][jj] = fmaf(a[ii], b[jj], acc[ii][jj]);
    }
    __syncthreads();
  }

  // Epilogue: dist^2 = acc (-2*cross) + G·P (Taylor Gram term) + ||zc||^2,
  // then logit -> stable softplus -> accumulate
  float lsum = 0.0f;
#pragma unroll
  for (int ii = 0; ii < 4; ++ii) {
    const int r = m0 + tm * 4 + ii;
    const float4 g0 = *(const float4*)(G16 + r * 16 + 0);
    const float4 g1 = *(const float4*)(G16 + r * 16 + 4);
    const float4 g2 = *(const float4*)(G16 + r * 16 + 8);
    const float4 g3 = *(const float4*)(G16 + r * 16 + 12);
    const float gr = gamma_rows[r];
    const int4 ev4 = *(const int4*)(events + (size_t)r * C_DIM + c0 + tn * 4);
    const int evs[4] = {ev4.x, ev4.y, ev4.z, ev4.w};
#pragma unroll
    for (int jj = 0; jj < 4; ++jj) {
      const int c = c0 + tn * 4 + jj;
      const float4 p0 = *(const float4*)(P16 + c * 16 + 0);
      const float4 p1 = *(const float4*)(P16 + c * 16 + 4);
      const float4 p2 = *(const float4*)(P16 + c * 16 + 8);
      const float4 p3 = *(const float4*)(P16 + c * 16 + 12);
      float t1 = g0.x * p0.x;
      t1 = fmaf(g0.y, p0.y, t1); t1 = fmaf(g0.z, p0.z, t1); t1 = fmaf(g0.w, p0.w, t1);
      t1 = fmaf(g1.x, p1.x, t1); t1 = fmaf(g1.y, p1.y, t1);
      t1 = fmaf(g1.z, p1.z, t1); t1 = fmaf(g1.w, p1.w, t1);
      t1 = fmaf(g2.x, p2.x, t1); t1 = fmaf(g2.y, p2.y, t1);
      t1 = fmaf(g2.z, p2.z, t1); t1 = fmaf(g2.w, p2.w, t1);
      t1 = fmaf(g3.x, p3.x, t1); t1 = fmaf(g3.y, p3.y, t1);
      t1 = fmaf(g3.z, p3.z, t1); t1 = fmaf(g3.w, p3.w, t1);
      const float d2 = acc[ii][jj] + t1 + nzc[c];
      const float dist = sqrtf(fmaxf(d2, 0.0f));
      const float logit = gr + gamma_cols[c] - dist;
      // -log_sigmoid(s*logit) = softplus(-s*logit); s=+1 iff event==1
      const float x = (evs[jj] == 1) ? -logit : logit;
      lsum += fmaxf(x, 0.0f) + __logf(1.0f + __expf(-fabsf(x)));
    }
  }

  // wave reduce + cross-wave reduce + one atomic per block
  for (int off = 32; off > 0; off >>= 1) lsum += __shfl_down(lsum, off);
  if ((t & 63) == 0) red[t >> 6] = lsum;
  __syncthreads();
  if (t == 0) atomicAdd(out, red[0] + red[1] + red[2] + red[3]);
}

extern "C" void kernel_launch(void* const* d_in, const int* in_sizes, int n_in,
                              void* d_out, int out_size, void* d_ws, size_t ws_size,
                              hipStream_t stream) {
  const int* events = (const int*)d_in[0];
  const float* col_times = (const float*)d_in[1];
  const float* z_rows = (const float*)d_in[2];
  const float* z_cols = (const float*)d_in[3];
  const float* gamma_rows = (const float*)d_in[4];
  const float* gamma_cols = (const float*)d_in[5];
  float* out = (float*)d_out;
  float* ws = (float*)d_ws;

  prep_rows_kernel<<<R_DIM, 64, 0, stream>>>(z_rows, ws, out);
  prep_cols_kernel<<<C_DIM, 64, 0, stream>>>(col_times, z_cols, ws);
  dim3 grid(C_DIM / BN, R_DIM / BM);
  pair_kernel<<<grid, 256, 0, stream>>>(events, z_rows, z_cols, gamma_rows,
                                        gamma_cols, ws, out);
}

// Round 2
// 99.124 us; speedup vs baseline: 1.2827x; 1.2827x over previous
//
#include <hip/hip_runtime.h>
#include <hip/hip_bf16.h>
#include <math.h>

// Problem constants: R,C,D,ORDER = 2048,2048,64,3; O=4
#define R_DIM 2048
#define C_DIM 2048
#define D_DIM 64
#define O_DIM 4
#define K_USED 272   // 256 cross terms + 16 Gram/coef-product terms
#define K_TOT 288    // padded to multiple of 32 (MFMA K-step)

typedef __attribute__((ext_vector_type(8))) short short8;   // bf16x8 frag (4 VGPR)
typedef __attribute__((ext_vector_type(4))) float floatx4;  // fp32x4 acc

// Workspace layout:
//   Ab: ushort[R][K_TOT]  bf16 A-matrix (z_rows by k<256; Gram 4x4 at 256..271; 0-pad)
//   Bb: ushort[C][K_TOT]  bf16 B-matrix (-2*coef_o*z_cols; coef outer-prods; 0-pad)
//   nzc: float[C]         ||z_col||^2
// Total: 2*2048*288*2 + 2048*4 = 2,367,488 B

__device__ __forceinline__ ushort f2bf(float f) {  // RNE float->bf16
  unsigned u = __float_as_uint(f);
  return (ushort)((u + 0x7FFFu + ((u >> 16) & 1u)) >> 16);
}

__device__ __forceinline__ void load16_lds(const void* g, void* l) {
  // global_load_lds_dwordx4: dest = wave-uniform lds base + lane*16
  auto gp = reinterpret_cast<const __attribute__((address_space(1))) unsigned int*>(
      reinterpret_cast<uintptr_t>(g));
  auto lp = reinterpret_cast<__attribute__((address_space(3))) unsigned int*>(
      (unsigned int)reinterpret_cast<uintptr_t>(l));
  __builtin_amdgcn_global_load_lds(gp, lp, 16, 0, 0);
}

// ---------------- prep: build bf16 A/B matrices + nzc, zero out[0] -----------
// blocks [0,512): rows (4 rows/block, 1 wave each)
// blocks [512,1024): cols (4 cols/block, 1 wave each)
__global__ void prep_kernel(const float* __restrict__ col_times,
                            const float* __restrict__ z_rows,
                            const float* __restrict__ z_cols,
                            ushort* __restrict__ Ab,
                            ushort* __restrict__ Bb,
                            float* __restrict__ nzc,
                            float* __restrict__ out) {
  const int b = blockIdx.x;
  const int t = threadIdx.x;
  const int w = t >> 6;
  const int lane = t & 63;

  if (b == 0 && t == 0) out[0] = 0.0f;  // runs before pair_kernel (stream order)

  if (b < 512) {
    const int r = b * 4 + w;
    float zv[O_DIM];
#pragma unroll
    for (int o = 0; o < O_DIM; ++o) {
      zv[o] = z_rows[(size_t)(o * R_DIM + r) * D_DIM + lane];
      Ab[(size_t)r * K_TOT + o * 64 + lane] = f2bf(zv[o]);
    }
    // Gram: 10 unique dots over D=64 via butterfly
    float g00 = zv[0] * zv[0], g01 = zv[0] * zv[1], g02 = zv[0] * zv[2],
          g03 = zv[0] * zv[3], g11 = zv[1] * zv[1], g12 = zv[1] * zv[2],
          g13 = zv[1] * zv[3], g22 = zv[2] * zv[2], g23 = zv[2] * zv[3],
          g33 = zv[3] * zv[3];
#pragma unroll
    for (int off = 32; off > 0; off >>= 1) {
      g00 += __shfl_xor(g00, off); g01 += __shfl_xor(g01, off);
      g02 += __shfl_xor(g02, off); g03 += __shfl_xor(g03, off);
      g11 += __shfl_xor(g11, off); g12 += __shfl_xor(g12, off);
      g13 += __shfl_xor(g13, off); g22 += __shfl_xor(g22, off);
      g23 += __shfl_xor(g23, off); g33 += __shfl_xor(g33, off);
    }
    if (lane == 0) {
      ushort* e = Ab + (size_t)r * K_TOT + 256;  // full 4x4 symmetric
      e[0] = f2bf(g00);  e[1] = f2bf(g01);  e[2] = f2bf(g02);  e[3] = f2bf(g03);
      e[4] = f2bf(g01);  e[5] = f2bf(g11);  e[6] = f2bf(g12);  e[7] = f2bf(g13);
      e[8] = f2bf(g02);  e[9] = f2bf(g12);  e[10] = f2bf(g22); e[11] = f2bf(g23);
      e[12] = f2bf(g03); e[13] = f2bf(g13); e[14] = f2bf(g23); e[15] = f2bf(g33);
    }
    if (lane < 16) Ab[(size_t)r * K_TOT + K_USED + lane] = 0;  // pad
  } else {
    const int c = (b - 512) * 4 + w;
    const float tt = col_times[c];
    float cf[4];
    cf[0] = 1.0f; cf[1] = tt; cf[2] = tt * tt * 0.5f;
    cf[3] = tt * tt * tt * (1.0f / 6.0f);
    const float zc = z_cols[(size_t)c * D_DIM + lane];
#pragma unroll
    for (int o = 0; o < O_DIM; ++o)
      Bb[(size_t)c * K_TOT + o * 64 + lane] = f2bf(-2.0f * cf[o] * zc);
    float q = zc * zc;
#pragma unroll
    for (int off = 32; off > 0; off >>= 1) q += __shfl_xor(q, off);
    if (lane == 0) {
      nzc[c] = q;
      ushort* e = Bb + (size_t)c * K_TOT + 256;
#pragma unroll
      for (int i = 0; i < 16; ++i) e[i] = f2bf(cf[i >> 2] * cf[i & 3]);
    }
    if (lane < 16) Bb[(size_t)c * K_TOT + K_USED + lane] = 0;  // pad
  }
}

// ---------------- main: bf16 MFMA GEMM(K=288) + fused softplus epilogue ------
// 128x128 block tile, 256 threads = 4 waves in 2x2, each wave 64x64 (4x4 MFMA
// tiles of 16x16x32). grid = 16x16 = 256 blocks = 1/CU.
__launch_bounds__(256, 2)
__global__ void pair_kernel(const int* __restrict__ events,
                            const float* __restrict__ gamma_rows,
                            const float* __restrict__ gamma_cols,
                            const ushort* __restrict__ Ab,
                            const ushort* __restrict__ Bb,
                            const float* __restrict__ nzc,
                            float* __restrict__ out) {
  __shared__ __align__(16) ushort As[128 * 32];  // [m][k] row-major, 64B rows
  __shared__ __align__(16) ushort Bs[128 * 32];  // [n][k]
  __shared__ float red[4];

  const int t = threadIdx.x;
  const int widx = t >> 6;
  const int lane = t & 63;
  const int m0 = blockIdx.y * 128;
  const int c0 = blockIdx.x * 128;
  const int wm = widx & 1;        // wave row in 2x2
  const int wn = widx >> 1;       // wave col
  const int lm = lane & 15;
  const int kg = lane >> 4;

  floatx4 acc[4][4];
#pragma unroll
  for (int i = 0; i < 4; ++i)
#pragma unroll
    for (int j = 0; j < 4; ++j) acc[i][j] = (floatx4){0.f, 0.f, 0.f, 0.f};

  // staging: 256 threads x 16B x 2 rounds = 8KB per matrix per K-tile
  const int srow = t >> 2;        // 0..63
  const int selem = (t & 3) * 8;  // k-offset in bf16 elems

  for (int kt = 0; kt < K_TOT; kt += 32) {
#pragma unroll
    for (int i = 0; i < 2; ++i) {
      const ushort* ga = Ab + (size_t)(m0 + srow + 64 * i) * K_TOT + kt + selem;
      load16_lds(ga, (char*)As + widx * 1024 + i * 4096);
      const ushort* gb = Bb + (size_t)(c0 + srow + 64 * i) * K_TOT + kt + selem;
      load16_lds(gb, (char*)Bs + widx * 1024 + i * 4096);
    }
    __syncthreads();

    short8 a[4], b[4];
#pragma unroll
    for (int mt = 0; mt < 4; ++mt)
      a[mt] = *(const short8*)(As + (wm * 64 + mt * 16 + lm) * 32 + kg * 8);
#pragma unroll
    for (int nt = 0; nt < 4; ++nt)
      b[nt] = *(const short8*)(Bs + (wn * 64 + nt * 16 + lm) * 32 + kg * 8);
#pragma unroll
    for (int mt = 0; mt < 4; ++mt)
#pragma unroll
      for (int nt = 0; nt < 4; ++nt)
        acc[mt][nt] = __builtin_amdgcn_mfma_f32_16x16x32_bf16(
            a[mt], b[nt], acc[mt][nt], 0, 0, 0);
    __syncthreads();
  }

  // Epilogue: dist^2 = acc + ||zc||^2 -> softplus((1-2e)*logit), local sum.
  // C/D layout (m89-verified): col = lane&15, row = (lane>>4)*4 + reg.
  float lsum = 0.0f;
#pragma unroll
  for (int nt = 0; nt < 4; ++nt) {
    const int c = c0 + wn * 64 + nt * 16 + lm;
    const float gc = gamma_cols[c];
    const float nz = nzc[c];
#pragma unroll
    for (int mt = 0; mt < 4; ++mt) {
      const int rbase = m0 + wm * 64 + mt * 16 + kg * 4;
      const floatx4 v = acc[mt][nt];
#pragma unroll
      for (int j = 0; j < 4; ++j) {
        const int r = rbase + j;
        const float d2 = v[j] + nz;
        const float dist = sqrtf(fmaxf(d2, 0.0f));
        const float logit = gamma_rows[r] + gc - dist;
        const int ev = events[(size_t)r * C_DIM + c];
        const float x = (ev == 1) ? -logit : logit;
        lsum += fmaxf(x, 0.0f) + __logf(1.0f + __expf(-fabsf(x)));
      }
    }
  }
#pragma unroll
  for (int off = 32; off > 0; off >>= 1) lsum += __shfl_down(lsum, off);
  if (lane == 0) red[widx] = lsum;
  __syncthreads();
  if (t == 0) atomicAdd(out, red[0] + red[1] + red[2] + red[3]);
}

extern "C" void kernel_launch(void* const* d_in, const int* in_sizes, int n_in,
                              void* d_out, int out_size, void* d_ws, size_t ws_size,
                              hipStream_t stream) {
  const int* events = (const int*)d_in[0];
  const float* col_times = (const float*)d_in[1];
  const float* z_rows = (const float*)d_in[2];
  const float* z_cols = (const float*)d_in[3];
  const float* gamma_rows = (const float*)d_in[4];
  const float* gamma_cols = (const float*)d_in[5];
  float* out = (float*)d_out;

  ushort* Ab = (ushort*)d_ws;
  ushort* Bb = Ab + (size_t)R_DIM * K_TOT;
  float* nzc = (float*)(Bb + (size_t)C_DIM * K_TOT);

  prep_kernel<<<1024, 256, 0, stream>>>(col_times, z_rows, z_cols, Ab, Bb, nzc, out);
  dim3 grid(C_DIM / 128, R_DIM / 128);
  pair_kernel<<<grid, 256, 0, stream>>>(events, gamma_rows, gamma_cols, Ab, Bb,
                                        nzc, out);
}

// Round 3
// 95.494 us; speedup vs baseline: 1.3315x; 1.0380x over previous
//
#include <hip/hip_runtime.h>
#include <hip/hip_bf16.h>
#include <math.h>

// Problem constants: R,C,D,ORDER = 2048,2048,64,3; O=4
#define R_DIM 2048
#define C_DIM 2048
#define D_DIM 64
#define O_DIM 4
#define K_USED 272   // 256 cross terms + 16 Gram/coef-product terms
#define K_TOT 288    // padded to multiple of 32 (MFMA K-step)
#define WB_WORDS (C_DIM / 64)  // 32 uint64 words per row of event bits

typedef __attribute__((ext_vector_type(8))) short short8;   // bf16x8 frag (4 VGPR)
typedef __attribute__((ext_vector_type(4))) float floatx4;  // fp32x4 acc

// Workspace layout (bytes):
//   Ab : ushort[R][K_TOT]      1,179,648   bf16 A (z_rows; Gram 4x4 at 256..271; pad)
//   Bb : ushort[C][K_TOT]      1,179,648   bf16 B (-2*coef_o*z_cols; coef prods; pad)
//   nzc: float[C]                  8,192   ||z_col||^2
//   Wb : uint64[R][WB_WORDS]     524,288   event bitmask, bit (c&63) of word c>>6
// Total ~2.88 MB (L2-resident)

__device__ __forceinline__ ushort f2bf(float f) {  // RNE float->bf16
  unsigned u = __float_as_uint(f);
  return (ushort)((u + 0x7FFFu + ((u >> 16) & 1u)) >> 16);
}

__device__ __forceinline__ void load16_lds(const void* g, void* l) {
  // global_load_lds_dwordx4: dest = wave-uniform lds base + lane*16
  auto gp = reinterpret_cast<const __attribute__((address_space(1))) unsigned int*>(
      reinterpret_cast<uintptr_t>(g));
  auto lp = reinterpret_cast<__attribute__((address_space(3))) unsigned int*>(
      (unsigned int)reinterpret_cast<uintptr_t>(l));
  __builtin_amdgcn_global_load_lds(gp, lp, 16, 0, 0);
}

// ---------------- prep: A/B matrices, nzc, event bitmask, zero out[0] --------
// blocks [0,512):     rows (4 rows/block, 1 wave each)
// blocks [512,1024):  cols (4 cols/block, 1 wave each)
// blocks [1024,3072): event bit-pack (1 row/block; 4 waves x 8 ballots)
__global__ void prep_kernel(const int* __restrict__ events,
                            const float* __restrict__ col_times,
                            const float* __restrict__ z_rows,
                            const float* __restrict__ z_cols,
                            ushort* __restrict__ Ab,
                            ushort* __restrict__ Bb,
                            float* __restrict__ nzc,
                            unsigned long long* __restrict__ Wb,
                            float* __restrict__ out) {
  const int b = blockIdx.x;
  const int t = threadIdx.x;
  const int w = t >> 6;
  const int lane = t & 63;

  if (b == 0 && t == 0) out[0] = 0.0f;  // stream order: runs before pair_kernel

  if (b < 512) {
    const int r = b * 4 + w;
    float zv[O_DIM];
#pragma unroll
    for (int o = 0; o < O_DIM; ++o) {
      zv[o] = z_rows[(size_t)(o * R_DIM + r) * D_DIM + lane];
      Ab[(size_t)r * K_TOT + o * 64 + lane] = f2bf(zv[o]);
    }
    float g00 = zv[0] * zv[0], g01 = zv[0] * zv[1], g02 = zv[0] * zv[2],
          g03 = zv[0] * zv[3], g11 = zv[1] * zv[1], g12 = zv[1] * zv[2],
          g13 = zv[1] * zv[3], g22 = zv[2] * zv[2], g23 = zv[2] * zv[3],
          g33 = zv[3] * zv[3];
#pragma unroll
    for (int off = 32; off > 0; off >>= 1) {
      g00 += __shfl_xor(g00, off); g01 += __shfl_xor(g01, off);
      g02 += __shfl_xor(g02, off); g03 += __shfl_xor(g03, off);
      g11 += __shfl_xor(g11, off); g12 += __shfl_xor(g12, off);
      g13 += __shfl_xor(g13, off); g22 += __shfl_xor(g22, off);
      g23 += __shfl_xor(g23, off); g33 += __shfl_xor(g33, off);
    }
    if (lane == 0) {
      ushort* e = Ab + (size_t)r * K_TOT + 256;  // full 4x4 symmetric
      e[0] = f2bf(g00);  e[1] = f2bf(g01);  e[2] = f2bf(g02);  e[3] = f2bf(g03);
      e[4] = f2bf(g01);  e[5] = f2bf(g11);  e[6] = f2bf(g12);  e[7] = f2bf(g13);
      e[8] = f2bf(g02);  e[9] = f2bf(g12);  e[10] = f2bf(g22); e[11] = f2bf(g23);
      e[12] = f2bf(g03); e[13] = f2bf(g13); e[14] = f2bf(g23); e[15] = f2bf(g33);
    }
    if (lane < 16) Ab[(size_t)r * K_TOT + K_USED + lane] = 0;  // pad
  } else if (b < 1024) {
    const int c = (b - 512) * 4 + w;
    const float tt = col_times[c];
    float cf[4];
    cf[0] = 1.0f; cf[1] = tt; cf[2] = tt * tt * 0.5f;
    cf[3] = tt * tt * tt * (1.0f / 6.0f);
    const float zc = z_cols[(size_t)c * D_DIM + lane];
#pragma unroll
    for (int o = 0; o < O_DIM; ++o)
      Bb[(size_t)c * K_TOT + o * 64 + lane] = f2bf(-2.0f * cf[o] * zc);
    float q = zc * zc;
#pragma unroll
    for (int off = 32; off > 0; off >>= 1) q += __shfl_xor(q, off);
    if (lane == 0) {
      nzc[c] = q;
      ushort* e = Bb + (size_t)c * K_TOT + 256;
#pragma unroll
      for (int i = 0; i < 16; ++i) e[i] = f2bf(cf[i >> 2] * cf[i & 3]);
    }
    if (lane < 16) Bb[(size_t)c * K_TOT + K_USED + lane] = 0;  // pad
  } else {
    // event bit-pack: one row per block, wave w covers cols [w*512, w*512+512)
    const int r = b - 1024;
    const int cbase = w * 512;
#pragma unroll
    for (int i = 0; i < 8; ++i) {
      const int col = cbase + i * 64 + lane;
      const int ev = events[(size_t)r * C_DIM + col];
      const unsigned long long mask = __ballot(ev == 1);
      if (lane == 0) Wb[r * WB_WORDS + (cbase >> 6) + i] = mask;
    }
  }
}

// ---------------- main: bf16 MFMA GEMM(K=288) + fused softplus epilogue ------
// 64x64 block tile, 256 threads = 4 waves in 2x2 (wave tile 32x32 = 2x2 MFMA
// tiles of 16x16x32). grid = 32x32 = 1024 blocks = 4 blocks/CU for latency
// overlap (1 block/CU in round 2 was the serial-K-loop bottleneck).
__launch_bounds__(256, 4)
__global__ void pair_kernel(const float* __restrict__ gamma_rows,
                            const float* __restrict__ gamma_cols,
                            const ushort* __restrict__ Ab,
                            const ushort* __restrict__ Bb,
                            const float* __restrict__ nzc,
                            const unsigned long long* __restrict__ Wb,
                            float* __restrict__ out) {
  __shared__ __align__(16) ushort As[64 * 32];  // [m][k], 64B rows
  __shared__ __align__(16) ushort Bs[64 * 32];  // [n][k]
  __shared__ float red[4];

  const int t = threadIdx.x;
  const int widx = t >> 6;
  const int lane = t & 63;
  const int m0 = blockIdx.y * 64;
  const int c0 = blockIdx.x * 64;
  const int wm = widx & 1;   // wave row in 2x2
  const int wn = widx >> 1;  // wave col
  const int lm = lane & 15;
  const int kg = lane >> 4;

  floatx4 acc[2][2];
#pragma unroll
  for (int i = 0; i < 2; ++i)
#pragma unroll
    for (int j = 0; j < 2; ++j) acc[i][j] = (floatx4){0.f, 0.f, 0.f, 0.f};

  const int srow = t >> 2;        // 0..63
  const int selem = (t & 3) * 8;  // k-offset (bf16 elems), 16B granules

  for (int kt = 0; kt < K_TOT; kt += 32) {
    load16_lds(Ab + (size_t)(m0 + srow) * K_TOT + kt + selem,
               (char*)As + widx * 1024);
    load16_lds(Bb + (size_t)(c0 + srow) * K_TOT + kt + selem,
               (char*)Bs + widx * 1024);
    __syncthreads();

    short8 a[2], b[2];
#pragma unroll
    for (int mt = 0; mt < 2; ++mt)
      a[mt] = *(const short8*)(As + (wm * 32 + mt * 16 + lm) * 32 + kg * 8);
#pragma unroll
    for (int nt = 0; nt < 2; ++nt)
      b[nt] = *(const short8*)(Bs + (wn * 32 + nt * 16 + lm) * 32 + kg * 8);
#pragma unroll
    for (int mt = 0; mt < 2; ++mt)
#pragma unroll
      for (int nt = 0; nt < 2; ++nt)
        acc[mt][nt] = __builtin_amdgcn_mfma_f32_16x16x32_bf16(
            a[mt], b[nt], acc[mt][nt], 0, 0, 0);
    __syncthreads();
  }

  // Epilogue. C/D layout (m89): col = lane&15, row = (lane>>4)*4 + reg.
  // Event bits: word Wb[r*32 + c0/64], bit = c&63 (c0 is 64-aligned).
  float gc[2], nz[2];
  int cbit[2];
#pragma unroll
  for (int nt = 0; nt < 2; ++nt) {
    const int c = c0 + wn * 32 + nt * 16 + lm;
    gc[nt] = gamma_cols[c];
    nz[nt] = nzc[c];
    cbit[nt] = c & 63;
  }
  const int wword = blockIdx.x;  // c0 >> 6
  float lsum = 0.0f;
#pragma unroll
  for (int mt = 0; mt < 2; ++mt) {
    const int rbase = m0 + wm * 32 + mt * 16 + kg * 4;
#pragma unroll
    for (int j = 0; j < 4; ++j) {
      const int r = rbase + j;
      const float gr = gamma_rows[r];
      const unsigned long long wbits = Wb[r * WB_WORDS + wword];
#pragma unroll
      for (int nt = 0; nt < 2; ++nt) {
        const float d2 = acc[mt][nt][j] + nz[nt];
        const float dist = sqrtf(fmaxf(d2, 0.0f));
        const float logit = gr + gc[nt] - dist;
        const int ev = (int)((wbits >> cbit[nt]) & 1ull);
        const float x = ev ? -logit : logit;  // softplus(-s*logit)
        lsum += fmaxf(x, 0.0f) + __logf(1.0f + __expf(-fabsf(x)));
      }
    }
  }
#pragma unroll
  for (int off = 32; off > 0; off >>= 1) lsum += __shfl_down(lsum, off);
  if (lane == 0) red[widx] = lsum;
  __syncthreads();
  if (t == 0) atomicAdd(out, red[0] + red[1] + red[2] + red[3]);
}

extern "C" void kernel_launch(void* const* d_in, const int* in_sizes, int n_in,
                              void* d_out, int out_size, void* d_ws, size_t ws_size,
                              hipStream_t stream) {
  const int* events = (const int*)d_in[0];
  const float* col_times = (const float*)d_in[1];
  const float* z_rows = (const float*)d_in[2];
  const float* z_cols = (const float*)d_in[3];
  const float* gamma_rows = (const float*)d_in[4];
  const float* gamma_cols = (const float*)d_in[5];
  float* out = (float*)d_out;

  ushort* Ab = (ushort*)d_ws;
  ushort* Bb = Ab + (size_t)R_DIM * K_TOT;
  float* nzc = (float*)(Bb + (size_t)C_DIM * K_TOT);
  unsigned long long* Wb = (unsigned long long*)(nzc + C_DIM);

  prep_kernel<<<3072, 256, 0, stream>>>(events, col_times, z_rows, z_cols, Ab,
                                        Bb, nzc, Wb, out);
  dim3 grid(C_DIM / 64, R_DIM / 64);
  pair_kernel<<<grid, 256, 0, stream>>>(gamma_rows, gamma_cols, Ab, Bb, nzc, Wb,
                                        out);
}